// Round 1
// baseline (494.592 us; speedup 1.0000x reference)
//
#include <hip/hip_runtime.h>
#include <math.h>

// HistogramBinningCalibrationByFeature
// Outputs (concatenated in d_out):
//   [0 .. N)      calibrated_prediction  (float32)
//   [N .. 2N)     bin_ids_data           (stored as float32 VALUES; exactly
//                                         representable, max 214999 < 2^24)

constexpr int kNumBins     = 5000;
constexpr int kNumSegments = 42;
constexpr int kNumInterval = (kNumSegments + 1) * kNumBins;  // 215000

__global__ __launch_bounds__(256) void hbc_kernel(
    const int*   __restrict__ seg_val,   // [N]
    const int*   __restrict__ seg_len,   // [N+1]
    const float* __restrict__ logit,     // [N]
    const float* __restrict__ bin_pos,   // [kNumInterval]
    const float* __restrict__ bin_num,   // [kNumInterval]
    const float* __restrict__ pos_w,     // [1]
    float*       __restrict__ out_pred,  // [N]
    float*       __restrict__ out_bin,   // [N] (float-encoded ids)
    int n)
{
    const float kStep = 0.0002f;  // float32(1.0/5000.0), matches jnp f32 STEP
    // log(positive_weight) computed in double -> correctly rounded f32
    const float lpw = (float)log((double)pos_w[0]);

    const int nvec   = n >> 2;                       // n is a multiple of 4
    const int stride = gridDim.x * blockDim.x;

    for (int v = blockIdx.x * blockDim.x + threadIdx.x; v < nvec; v += stride) {
        const int i = v << 2;

        const float4 lg  = *reinterpret_cast<const float4*>(logit + i);
        const int4   sl  = *reinterpret_cast<const int4*>(seg_len + i);
        const int    sl4 = seg_len[i + 4];

        float l[4] = {lg.x, lg.y, lg.z, lg.w};
        int   s[5] = {sl.x, sl.y, sl.z, sl.w, sl4};

        float4 op, ob;
        float* opp = &op.x;
        float* obp = &ob.x;

        #pragma unroll
        for (int j = 0; j < 4; ++j) {
            // origin_prediction = sigmoid(logit + log(pw)), computed in
            // double then rounded -> ~correctly-rounded f32 sigmoid.
            const float  x  = l[j] + lpw;            // f32 add, like the ref
            const double pd = 1.0 / (1.0 + exp(-(double)x));
            const float  p  = (float)pd;

            // dense segment id
            const int  off   = s[j];
            const bool valid = s[j + 1] > off;
            int ds = 0;
            if (valid) {
                const int sv = seg_val[off] + 1;     // predicated gather
                ds = (sv > kNumSegments) ? 0 : sv;
            }

            // bin id: (ceil(p/STEP) - 1) + ds*NUM_BINS, all f32 like the ref
            const float q   = ceilf(p / kStep) - 1.0f;
            const int   bin = (int)q + ds * kNumBins;

            // gather with clamped index (jnp gather clamps OOB)
            int idx = bin;
            idx = idx < 0 ? 0 : idx;
            idx = idx > (kNumInterval - 1) ? (kNumInterval - 1) : idx;
            const float cp = bin_pos[idx];
            const float cn = bin_num[idx];

            const float ctr = (cp / cn) * 0.9995f + p * 0.0005f;
            opp[j] = (cn > 0.0f) ? ctr : p;
            obp[j] = (float)bin;                     // store id as f32 value
        }

        *reinterpret_cast<float4*>(out_pred + i) = op;
        *reinterpret_cast<float4*>(out_bin  + i) = ob;
    }
}

extern "C" void kernel_launch(void* const* d_in, const int* in_sizes, int n_in,
                              void* d_out, int out_size, void* d_ws, size_t ws_size,
                              hipStream_t stream) {
    const int*   seg_val = (const int*)  d_in[0];  // segment_value   [N]
    const int*   seg_len = (const int*)  d_in[1];  // segment_lengths [N+1]
    const float* logit   = (const float*)d_in[2];  // logit           [N]
    const float* bin_pos = (const float*)d_in[3];  // bin_num_positives
    const float* bin_num = (const float*)d_in[4];  // bin_num_examples
    const float* pos_w   = (const float*)d_in[5];  // positive_weight [1]

    const int n = in_sizes[2];                     // NUM_LOGITS
    float* out_pred = (float*)d_out;
    float* out_bin  = (float*)d_out + n;

    const int threads = 256;
    const int nvec    = n >> 2;
    int blocks = (nvec + threads - 1) / threads;
    if (blocks > 2048) blocks = 2048;              // grid-stride the rest

    hbc_kernel<<<blocks, threads, 0, stream>>>(
        seg_val, seg_len, logit, bin_pos, bin_num, pos_w,
        out_pred, out_bin, n);
}

// Round 2
// 389.934 us; speedup vs baseline: 1.2684x; 1.2684x over previous
//
#include <hip/hip_runtime.h>
#include <math.h>

// HistogramBinningCalibrationByFeature
// d_out layout: [0..N) calibrated_prediction (f32) | [N..2N) bin ids (f32-encoded)
//
// Strategy: prep kernel folds the two bin tables into one ratio table in d_ws
// (r = 0.9995*(pos/num), NaN if num<=0) -> ONE L2 gather per element instead
// of two, no per-element division. Main kernel: 8 elem/thread, f32 sigmoid,
// non-temporal streaming loads/stores to keep the ratio table L2-resident.

constexpr int kNumBins     = 5000;
constexpr int kNumSegments = 42;
constexpr int kNumInterval = (kNumSegments + 1) * kNumBins;  // 215000

typedef float f32x4 __attribute__((ext_vector_type(4)));
typedef int   i32x4 __attribute__((ext_vector_type(4)));

__global__ __launch_bounds__(256) void ratio_kernel(
    const float* __restrict__ bin_pos,
    const float* __restrict__ bin_num,
    const float* __restrict__ pos_w,
    float*       __restrict__ ratio)   // [kNumInterval + 1]
{
    const int i = blockIdx.x * 256 + threadIdx.x;
    if (i < kNumInterval) {
        const float nm = bin_num[i];
        // Same op order as ref: (pos/num)*W. NaN sentinel encodes "invalid".
        const float r = (nm > 0.0f) ? (bin_pos[i] / nm) * 0.9995f
                                    : __int_as_float(0x7FC00000);
        ratio[i] = r;
    }
    if (i == 0) {
        // log(positive_weight) in double -> correctly-rounded f32, once.
        ratio[kNumInterval] = (float)log((double)pos_w[0]);
    }
}

__global__ __launch_bounds__(256) void hbc_kernel8(
    const int*   __restrict__ seg_val,   // [N]
    const int*   __restrict__ seg_len,   // [N+1]
    const float* __restrict__ logit,     // [N]
    const float* __restrict__ ratio,     // [kNumInterval+1] (in ws)
    float*       __restrict__ out_pred,  // [N]
    float*       __restrict__ out_bin,   // [N]
    int n)
{
    const float kStep = 0.0002f;                 // f32(1/5000), as in ref
    const float lpw   = ratio[kNumInterval];     // uniform broadcast load

    const long t    = (long)blockIdx.x * blockDim.x + threadIdx.x;
    const long base = t * 8;
    if (base >= n) return;

    if (base + 8 <= n) {
        // ---- issue all streaming loads up front (independent) ----
        const f32x4 L0 = __builtin_nontemporal_load((const f32x4*)(logit   + base));
        const f32x4 L1 = __builtin_nontemporal_load((const f32x4*)(logit   + base + 4));
        const i32x4 S0 = __builtin_nontemporal_load((const i32x4*)(seg_len + base));
        const i32x4 S1 = __builtin_nontemporal_load((const i32x4*)(seg_len + base + 4));
        const int   s8 = seg_len[base + 8];

        const int   s[9] = {S0[0], S0[1], S0[2], S0[3], S1[0], S1[1], S1[2], S1[3], s8};
        const float l[8] = {L0[0], L0[1], L0[2], L0[3], L1[0], L1[1], L1[2], L1[3]};

        // ---- segment-id gathers (sorted indices -> cache friendly) ----
        int ds[8];
        #pragma unroll
        for (int j = 0; j < 8; ++j) {
            int d = 0;
            if (s[j + 1] > s[j]) {
                const int sv = seg_val[s[j]] + 1;
                d = (sv > kNumSegments) ? 0 : sv;
            }
            ds[j] = d;
        }

        // ---- f32 sigmoid + bin id ----
        float p[8]; int bin[8];
        #pragma unroll
        for (int j = 0; j < 8; ++j) {
            const float x  = l[j] + lpw;
            const float pf = 1.0f / (1.0f + expf(-x));
            p[j]   = pf;
            bin[j] = (int)(ceilf(pf / kStep) - 1.0f) + ds[j] * kNumBins;
        }

        // ---- single fused-ratio gather per element ----
        float r[8];
        #pragma unroll
        for (int j = 0; j < 8; ++j) {
            int idx = bin[j];
            idx = idx < 0 ? 0 : idx;
            idx = idx > (kNumInterval - 1) ? (kNumInterval - 1) : idx;
            r[j] = ratio[idx];
        }

        // ---- epilogue + streaming stores ----
        f32x4 o0, o1, b0, b1;
        #pragma unroll
        for (int j = 0; j < 4; ++j) {
            const float ra = r[j],     rb = r[j + 4];
            o0[j] = (ra == ra) ? (ra + p[j]     * 0.0005f) : p[j];
            o1[j] = (rb == rb) ? (rb + p[j + 4] * 0.0005f) : p[j + 4];
            b0[j] = (float)bin[j];
            b1[j] = (float)bin[j + 4];
        }
        __builtin_nontemporal_store(o0, (f32x4*)(out_pred + base));
        __builtin_nontemporal_store(o1, (f32x4*)(out_pred + base + 4));
        __builtin_nontemporal_store(b0, (f32x4*)(out_bin  + base));
        __builtin_nontemporal_store(b1, (f32x4*)(out_bin  + base + 4));
    } else {
        // generic tail (not hit for N=20M, kept for safety)
        for (long i = base; i < n; ++i) {
            const float x  = logit[i] + lpw;
            const float pf = 1.0f / (1.0f + expf(-x));
            int d = 0;
            if (seg_len[i + 1] > seg_len[i]) {
                const int sv = seg_val[seg_len[i]] + 1;
                d = (sv > kNumSegments) ? 0 : sv;
            }
            const int bin = (int)(ceilf(pf / kStep) - 1.0f) + d * kNumBins;
            int idx = bin < 0 ? 0 : (bin > kNumInterval - 1 ? kNumInterval - 1 : bin);
            const float rr = ratio[idx];
            out_pred[i] = (rr == rr) ? (rr + pf * 0.0005f) : pf;
            out_bin[i]  = (float)bin;
        }
    }
}

// Fallback (ws too small): direct two-table gather, still 8/thread + f32 path.
__global__ __launch_bounds__(256) void hbc_direct8(
    const int*   __restrict__ seg_val,
    const int*   __restrict__ seg_len,
    const float* __restrict__ logit,
    const float* __restrict__ bin_pos,
    const float* __restrict__ bin_num,
    const float* __restrict__ pos_w,
    float*       __restrict__ out_pred,
    float*       __restrict__ out_bin,
    int n)
{
    const float kStep = 0.0002f;
    const float lpw   = logf(pos_w[0]);
    const long base   = ((long)blockIdx.x * blockDim.x + threadIdx.x) * 8;
    for (long i = base; i < base + 8 && i < n; ++i) {
        const float x  = logit[i] + lpw;
        const float pf = 1.0f / (1.0f + expf(-x));
        int d = 0;
        if (seg_len[i + 1] > seg_len[i]) {
            const int sv = seg_val[seg_len[i]] + 1;
            d = (sv > kNumSegments) ? 0 : sv;
        }
        const int bin = (int)(ceilf(pf / kStep) - 1.0f) + d * kNumBins;
        int idx = bin < 0 ? 0 : (bin > kNumInterval - 1 ? kNumInterval - 1 : bin);
        const float cp = bin_pos[idx];
        const float cn = bin_num[idx];
        const float ctr = (cp / cn) * 0.9995f + pf * 0.0005f;
        out_pred[i] = (cn > 0.0f) ? ctr : pf;
        out_bin[i]  = (float)bin;
    }
}

extern "C" void kernel_launch(void* const* d_in, const int* in_sizes, int n_in,
                              void* d_out, int out_size, void* d_ws, size_t ws_size,
                              hipStream_t stream) {
    const int*   seg_val = (const int*)  d_in[0];
    const int*   seg_len = (const int*)  d_in[1];
    const float* logit   = (const float*)d_in[2];
    const float* bin_pos = (const float*)d_in[3];
    const float* bin_num = (const float*)d_in[4];
    const float* pos_w   = (const float*)d_in[5];

    const int n = in_sizes[2];
    float* out_pred = (float*)d_out;
    float* out_bin  = (float*)d_out + n;

    const size_t ws_needed = (size_t)(kNumInterval + 1) * sizeof(float);
    const int threads = 256;
    const int blocks_main = (int)((((long)n + 7) / 8 + threads - 1) / threads);

    if (ws_size >= ws_needed) {
        float* ratio = (float*)d_ws;
        const int blocks_prep = (kNumInterval + threads - 1) / threads;
        ratio_kernel<<<blocks_prep, threads, 0, stream>>>(bin_pos, bin_num, pos_w, ratio);
        hbc_kernel8<<<blocks_main, threads, 0, stream>>>(
            seg_val, seg_len, logit, ratio, out_pred, out_bin, n);
    } else {
        hbc_direct8<<<blocks_main, threads, 0, stream>>>(
            seg_val, seg_len, logit, bin_pos, bin_num, pos_w, out_pred, out_bin, n);
    }
}